// Round 16
// baseline (686.340 us; speedup 1.0000x reference)
//
#include <hip/hip_runtime.h>

#define NBOX 4000
#define NPAD 4096
#define BATCH 8
#define WPR 64          // 64-bit words per suppression row
#define MAXK 300
#define GRIDN 256
#define BLKT 1024

typedef unsigned long long u64;

// Static device scratch (deterministic: every consulted value is rewritten
// each call — g_colT/g_colTB are zeroed in the sort phase before iou ORs in).
__device__ u64 g_sup[BATCH][NPAD][WPR];            // ~16.8 MB full rows
__device__ u64 g_colT[BATCH][66][64];              // transposed 64x64 diag blocks
__device__ u64 g_colTB[BATCH][33][64];             // transposed bank0->bank1 blocks
__device__ float4 g_sorted[BATCH][NPAD];           // sorted boxes + sentinels
__device__ float g_area[BATCH][NPAD];              // precomputed areas (0 for pad)
__device__ int g_nvalid[BATCH];

// Two-level sense-reversing grid barrier. Self-resetting (counters return to
// 0; generation increases monotonically) -> deterministic across graph
// replays. __threadfence() on both sides replaces the cache flush/inv that
// kernel-dispatch boundaries used to provide (cross-XCD visibility).
__device__ unsigned g_bar_sub[8 * 16];   // padded: one 64B line per group
__device__ unsigned g_bar_top;
__device__ unsigned g_bar_gen;

__device__ __forceinline__ void gridBarrier() {
    __threadfence();
    __syncthreads();
    if (threadIdx.x == 0) {
        const unsigned gen = __hip_atomic_load(&g_bar_gen, __ATOMIC_ACQUIRE, __HIP_MEMORY_SCOPE_AGENT);
        const int grp = blockIdx.x & 7;
        const unsigned prev = __hip_atomic_fetch_add(&g_bar_sub[grp * 16], 1u,
                                                     __ATOMIC_ACQ_REL, __HIP_MEMORY_SCOPE_AGENT);
        if (prev + 1u == (GRIDN / 8)) {
            __hip_atomic_store(&g_bar_sub[grp * 16], 0u, __ATOMIC_RELAXED, __HIP_MEMORY_SCOPE_AGENT);
            const unsigned p2 = __hip_atomic_fetch_add(&g_bar_top, 1u,
                                                       __ATOMIC_ACQ_REL, __HIP_MEMORY_SCOPE_AGENT);
            if (p2 + 1u == 8u) {
                __hip_atomic_store(&g_bar_top, 0u, __ATOMIC_RELAXED, __HIP_MEMORY_SCOPE_AGENT);
                __hip_atomic_fetch_add(&g_bar_gen, 1u, __ATOMIC_RELEASE, __HIP_MEMORY_SCOPE_AGENT);
            } else {
                while (__hip_atomic_load(&g_bar_gen, __ATOMIC_ACQUIRE, __HIP_MEMORY_SCOPE_AGENT) == gen)
                    __builtin_amdgcn_s_sleep(2);
            }
        } else {
            while (__hip_atomic_load(&g_bar_gen, __ATOMIC_ACQUIRE, __HIP_MEMORY_SCOPE_AGENT) == gen)
                __builtin_amdgcn_s_sleep(2);
        }
    }
    __syncthreads();
    __threadfence();
}

__device__ __forceinline__ unsigned int rdlu(unsigned int v, int l) {
    return (unsigned int)__builtin_amdgcn_readlane((int)v, l);
}
__device__ __forceinline__ u64 rdl64(u64 v, int l) {
    const unsigned lo = rdlu((unsigned)v, l);
    const unsigned hi = rdlu((unsigned)(v >> 32), l);
    return ((u64)hi << 32) | lo;
}

#define SORT_T 1024
#define EPT 4
#define HP2 1088        // hist pitch (u16 entries per digit row)

// ---------------------------------------------------------------------------
// ONE cooperative kernel, 256 blocks x 1024 threads (83 KB LDS -> exactly
// 1 block/CU -> all 256 co-resident; cooperative launch validates this).
// Phase A: R15 radix sort verbatim (blocks 0..7, one per batch).
// Phase B: R15 iou verbatim, all 4096 waves, wave w handles ids {w, w+4096..}.
// Phase C: R15 nms verbatim (wave 0 of blocks 0..7).
// ---------------------------------------------------------------------------
__global__ __launch_bounds__(BLKT) void mega_kernel(const float* __restrict__ props,
                                                    const float* __restrict__ scores,
                                                    float* __restrict__ out) {
    __shared__ unsigned int K0[NPAD], K1[NPAD];        // 32 KB
    __shared__ unsigned short P0[NPAD], P1[NPAD];      // 16 KB
    __shared__ unsigned short Hs[16 * HP2];            // 34 KB
    __shared__ unsigned int sWT[16];
    __shared__ int s_cnt;
    __shared__ int sIdx[128];

    const int tid = threadIdx.x;

    // ================= PHASE A: sort (blocks 0..7) =================
    if (blockIdx.x < BATCH) {
        const int b = blockIdx.x;
        if (tid == 0) s_cnt = 0;
        __syncthreads();

        int localc = 0;
        {
            const int n0 = tid * EPT;
            unsigned int kk[EPT];
            #pragma unroll
            for (int e = 0; e < EPT; ++e) {
                const int n = n0 + e;
                unsigned int k = 0xFFFFFFu;
                if (n < NBOX) {
                    const float2 sc = *reinterpret_cast<const float2*>(scores + ((size_t)b * NBOX + n) * 2);
                    const float4 p  = *reinterpret_cast<const float4*>(props  + ((size_t)b * NBOX + n) * 4);
                    const float fg = sc.y;
                    const float w = __fsub_rn(p.z, p.x);
                    const float h = __fsub_rn(p.w, p.y);
                    if ((fg > 0.5f) && (w >= 16.0f) && (h >= 16.0f)) {
                        k = 0x3F800000u - __float_as_uint(fg);
                        localc++;
                    }
                }
                kk[e] = k;
            }
            *reinterpret_cast<uint4*>(&K0[n0]) = make_uint4(kk[0], kk[1], kk[2], kk[3]);
            ushort4 pp;
            pp.x = (unsigned short)(n0 + 0); pp.y = (unsigned short)(n0 + 1);
            pp.z = (unsigned short)(n0 + 2); pp.w = (unsigned short)(n0 + 3);
            *reinterpret_cast<ushort4*>(&P0[n0]) = pp;
        }
        for (int off = 32; off > 0; off >>= 1) localc += __shfl_down(localc, off);
        if ((tid & 63) == 0) atomicAdd(&s_cnt, localc);

        unsigned int kr[EPT];
        unsigned short pr[EPT];

        for (int pass = 0; pass < 6; ++pass) {
            const int shift = pass * 4;
            const unsigned int*   ksrc = (pass & 1) ? K1 : K0;
            unsigned int*         kdst = (pass & 1) ? K0 : K1;
            const unsigned short* psrc = (pass & 1) ? P1 : P0;
            unsigned short*       pdst = (pass & 1) ? P0 : P1;

            for (int hh = tid; hh < (16 * HP2) / 2; hh += SORT_T)
                reinterpret_cast<unsigned int*>(Hs)[hh] = 0;
            __syncthreads();

            {
                const uint4 kv = *reinterpret_cast<const uint4*>(&ksrc[tid * EPT]);
                kr[0] = kv.x; kr[1] = kv.y; kr[2] = kv.z; kr[3] = kv.w;
                const ushort4 pv = *reinterpret_cast<const ushort4*>(&psrc[tid * EPT]);
                pr[0] = pv.x; pr[1] = pv.y; pr[2] = pv.z; pr[3] = pv.w;
            }
            #pragma unroll
            for (int e = 0; e < EPT; ++e) {
                const unsigned int d = (kr[e] >> shift) & 15u;
                Hs[d * HP2 + tid]++;
            }
            __syncthreads();

            {
                const int d  = tid >> 6;
                const int t0 = (tid & 63) * 16;
                unsigned short* row = &Hs[d * HP2];
                unsigned int sum = 0;
                #pragma unroll
                for (int e = 0; e < 16; ++e) {
                    const unsigned int v = row[t0 + e];
                    row[t0 + e] = (unsigned short)sum;
                    sum += v;
                }
                unsigned int x = sum;
                #pragma unroll
                for (int off = 1; off < 64; off <<= 1) {
                    const unsigned int y = __shfl_up(x, off);
                    if ((tid & 63) >= off) x += y;
                }
                const int wid = tid >> 6;
                if ((tid & 63) == 63) sWT[wid] = x;
                __syncthreads();
                unsigned int base = x - sum;
                for (int w = 0; w < wid; ++w) base += sWT[w];
                #pragma unroll
                for (int e = 0; e < 16; ++e) row[t0 + e] += (unsigned short)base;
            }
            __syncthreads();

            #pragma unroll
            for (int e = 0; e < EPT; ++e) {
                const unsigned int d = (kr[e] >> shift) & 15u;
                const unsigned int pos = Hs[d * HP2 + tid]++;
                kdst[pos] = kr[e];
                pdst[pos] = pr[e];
            }
            __syncthreads();
        }

        const int nv = s_cnt;
        if (tid == 0) g_nvalid[b] = nv;
        {
            const int p0 = tid * EPT;
            const ushort4 pv = *reinterpret_cast<const ushort4*>(&P0[p0]);
            const unsigned short pe[EPT] = {pv.x, pv.y, pv.z, pv.w};
            #pragma unroll
            for (int e = 0; e < EPT; ++e) {
                const int p = p0 + e;
                if (p < nv) {
                    const float4 bx = *reinterpret_cast<const float4*>(props + ((size_t)b * NBOX + pe[e]) * 4);
                    g_sorted[b][p] = bx;
                    g_area[b][p] = __fmul_rn(__fsub_rn(bx.z, bx.x), __fsub_rn(bx.w, bx.y));
                } else {
                    g_sorted[b][p] = make_float4(2e9f, 2e9f, 2e9f, 2e9f);
                    g_area[b][p] = 0.0f;
                }
            }
        }
        for (int z = tid; z < 66 * 64; z += SORT_T) (&g_colT[b][0][0])[z] = 0ull;
        for (int z = tid; z < 33 * 64; z += SORT_T) (&g_colTB[b][0][0])[z] = 0ull;
    }

    gridBarrier();

    // ================= PHASE B: iou (all 4096 waves) =================
    {
        const int lane = tid & 63;
        const int wave = blockIdx.x * (BLKT / 64) + (tid >> 6);
        const double C = 0.5 - 0x1p-26;    // exact rounding boundary of 0.5

        for (int id = wave; id < BATCH * NPAD; id += GRIDN * (BLKT / 64)) {
            const int b = id >> 12;
            const int i = id & (NPAD - 1);
            const int nv = g_nvalid[b];
            if (i >= nv) continue;
            const int c0 = i >> 6;
            const int W = (nv + 63) >> 6;

            const float4 bi = g_sorted[b][i];
            const float areai = g_area[b][i];

            u64 myword = 0ull;
            // peeled diagonal chunk c = c0 (the only chunk needing j > i)
            {
                const int j = (c0 << 6) + lane;
                const float4 bj = g_sorted[b][j];
                const float areaj = g_area[b][j];
                const float xi1 = fmaxf(bi.x, bj.x);
                const float yi1 = fmaxf(bi.y, bj.y);
                const float xi2 = fminf(bi.z, bj.z);
                const float yi2 = fminf(bi.w, bj.w);
                const float iw = fmaxf(__fsub_rn(xi2, xi1), 0.0f);
                const float ih = fmaxf(__fsub_rn(yi2, yi1), 0.0f);
                const float inter = __fmul_rn(iw, ih);
                const float uni = __fsub_rn(__fadd_rn(areai, areaj), inter);
                const bool pred = ((double)inter >= (double)uni * C) && (j > i);
                const u64 wd = __ballot(pred);
                if (lane == c0) myword = wd;
                const u64 contrib = ((wd >> lane) & 1ull) << (i & 63);
                if (contrib) atomicOr(&g_colT[b][c0][lane], contrib);
            }
            // off-diagonal chunks: j > i automatic, sentinels handle j >= nv
            for (int c = c0 + 1; c < W; ++c) {
                const int j = (c << 6) + lane;
                const float4 bj = g_sorted[b][j];
                const float areaj = g_area[b][j];
                const float xi1 = fmaxf(bi.x, bj.x);
                const float yi1 = fmaxf(bi.y, bj.y);
                const float xi2 = fminf(bi.z, bj.z);
                const float yi2 = fminf(bi.w, bj.w);
                const float iw = fmaxf(__fsub_rn(xi2, xi1), 0.0f);
                const float ih = fmaxf(__fsub_rn(yi2, yi1), 0.0f);
                const float inter = __fmul_rn(iw, ih);
                const float uni = __fsub_rn(__fadd_rn(areai, areaj), inter);
                const bool pred = ((double)inter >= (double)uni * C);
                const u64 wd = __ballot(pred);
                if (lane == c) myword = wd;
                if (c == c0 + 1 && !(c0 & 1)) {
                    const u64 contrib = ((wd >> lane) & 1ull) << (i & 63);
                    if (contrib) atomicOr(&g_colTB[b][i >> 7][lane], contrib);
                }
            }
            g_sup[b][i][lane] = myword;
        }
    }

    gridBarrier();

    // ================= PHASE C: nms (wave 0 of blocks 0..7) =================
    if (blockIdx.x < BATCH && tid < 64) {
        const int b = blockIdx.x;
        const int lane = tid;
        int nv = g_nvalid[b];
        if (nv > NBOX) nv = NBOX;
        float4* outv = reinterpret_cast<float4*>(out) + (size_t)b * MAXK;
        const u64* supb = &g_sup[b][0][0];

        for (int s = lane; s < MAXK; s += 64)
            outv[s] = make_float4(0.0f, 0.0f, 0.0f, 0.0f);

        u64 removed = 0ull;
        int kept = 0;
        const int nsb = (nv + 127) >> 7;    // <= 32

        u64 cA = g_colT[b][0][lane];
        u64 cB = g_colT[b][1][lane];
        u64 cC = g_colTB[b][0][lane];

        for (int s = 0; s < nsb && kept < MAXK; ++s) {
            const int base = s << 7;
            const u64 nA = g_colT[b][2 * s + 2][lane];
            const u64 nB = g_colT[b][2 * s + 3][lane];
            const u64 nC = g_colTB[b][s + 1][lane];

            const u64 wv0 = rdl64(removed, 2 * s);
            const u64 wv1 = rdl64(removed, 2 * s + 1);
            const int aliveA = (int)((~wv0 >> lane) & 1ull) & (int)(base + lane < nv);
            const int aliveB = (int)((~wv1 >> lane) & 1ull) & (int)(base + 64 + lane < nv);

            u64 balA = __ballot(aliveA != 0);
            u64 balB = __ballot(aliveB != 0);
            while (balA | balB) {
                const int supA = ((cA & balA) != 0ull);
                const int supB = (((cC & balA) | (cB & balB)) != 0ull);
                const u64 nbA = __ballot((aliveA & (supA ^ 1)) != 0);
                const u64 nbB = __ballot((aliveB & (supB ^ 1)) != 0);
                if (nbA == balA && nbB == balB) break;
                balA = nbA; balB = nbB;
            }

            int m = __popcll(balA) + __popcll(balB);
            const int cap = MAXK - kept;
            while (m > cap) {
                if (balB) balB &= ~(1ull << (63 - __builtin_clzll(balB)));
                else      balA &= ~(1ull << (63 - __builtin_clzll(balA)));
                --m;
            }

            if (m > 0) {
                const int mA = __popcll(balA);
                unsigned rA = __builtin_amdgcn_mbcnt_lo((unsigned)balA, 0u);
                rA = __builtin_amdgcn_mbcnt_hi((unsigned)(balA >> 32), rA);
                if ((balA >> lane) & 1ull) sIdx[rA] = base + lane;
                unsigned rB = __builtin_amdgcn_mbcnt_lo((unsigned)balB, 0u);
                rB = __builtin_amdgcn_mbcnt_hi((unsigned)(balB >> 32), rB);
                if ((balB >> lane) & 1ull) sIdx[mA + rB] = base + 64 + lane;

                {
                    const int m0 = (m < 64) ? m : 64;
                    if (lane < m0) outv[kept + lane] = g_sorted[b][sIdx[lane]];
                    if (m > 64 && lane < m - 64) outv[kept + 64 + lane] = g_sorted[b][sIdx[64 + lane]];
                }

                if (kept + m < MAXK && s + 1 < nsb) {
                    for (int t = 0; t < m; t += 32) {
#define LDW(j) u64 v##j; {                                                      \
                            int tt = t + j; if (tt >= m) tt = m - 1;            \
                            const int it = sIdx[tt];                            \
                            v##j = supb[(size_t)it * WPR + lane];               }
                        LDW(0)  LDW(1)  LDW(2)  LDW(3)  LDW(4)  LDW(5)  LDW(6)  LDW(7)
                        LDW(8)  LDW(9)  LDW(10) LDW(11) LDW(12) LDW(13) LDW(14) LDW(15)
                        LDW(16) LDW(17) LDW(18) LDW(19) LDW(20) LDW(21) LDW(22) LDW(23)
                        LDW(24) LDW(25) LDW(26) LDW(27) LDW(28) LDW(29) LDW(30) LDW(31)
#undef LDW
                        const u64 o0 = ((v0 | v1) | (v2 | v3)) | ((v4 | v5) | (v6 | v7));
                        const u64 o1 = ((v8 | v9) | (v10 | v11)) | ((v12 | v13) | (v14 | v15));
                        const u64 o2 = ((v16 | v17) | (v18 | v19)) | ((v20 | v21) | (v22 | v23));
                        const u64 o3 = ((v24 | v25) | (v26 | v27)) | ((v28 | v29) | (v30 | v31));
                        removed |= (o0 | o1) | (o2 | o3);
                    }
                }
                kept += m;
            }
            cA = nA; cB = nB; cC = nC;
        }
    }
}

extern "C" void kernel_launch(void* const* d_in, const int* in_sizes, int n_in,
                              void* d_out, int out_size, void* d_ws, size_t ws_size,
                              hipStream_t stream) {
    const float* props  = (const float*)d_in[0];   // (8,4000,4) f32
    const float* scores = (const float*)d_in[1];   // (8,4000,2) f32
    float* out = (float*)d_out;                    // (8,300,4) f32

    void* args[3] = {(void*)&props, (void*)&scores, (void*)&out};
    hipLaunchCooperativeKernel((void*)mega_kernel, dim3(GRIDN), dim3(BLKT),
                               args, 0, stream);
}

// Round 17
// 333.187 us; speedup vs baseline: 2.0599x; 2.0599x over previous
//
#include <hip/hip_runtime.h>

#define NBOX 4000
#define NPAD 4096
#define BATCH 8
#define WPR 64          // 64-bit words per suppression row
#define MAXK 300

typedef unsigned long long u64;

// Static device scratch (deterministic: every consulted value is rewritten
// each call — colT/colTB/done are zeroed in sort (dispatch 1) before use).
__device__ u64 g_sup[BATCH][NPAD][WPR];            // ~16.8 MB full rows (MALL-resident via agent stores)
__device__ u64 g_colT[BATCH][66][64];              // transposed 64x64 diag blocks
__device__ u64 g_colTB[BATCH][33][64];             // transposed bank0->bank1 blocks
__device__ float4 g_sorted[BATCH][NPAD];           // sorted boxes + sentinels
__device__ float g_area[BATCH][NPAD];              // precomputed areas (0 for pad)
__device__ int g_nvalid[BATCH];
__device__ unsigned g_done[BATCH][32][16];         // per-SB completion counters (64B padded)

// ---------------------------------------------------------------------------
// Kernel 1: per-batch stable LSD radix sort, 1024 threads x EPT=4 (proven).
// Key k = 0x3F800000 - bits(fg): valid => fg > 0.5 => k in (0, 0x800000),
// fits 24 bits -> 6 passes x 4 bits. Invalid/pad k = 0xFFFFFF sorts last.
// Blocked ownership + digit-major scan preserves jnp.argsort stability.
// Epilogue: sorted boxes, SENTINEL boxes (2e9 -> pred exactly false) for
// p >= nv, per-box areas, zeroes g_colT/g_colTB/g_done (the dispatch
// boundary publishes all of this to the fused kernel).
// ---------------------------------------------------------------------------
#define SORT_T 1024
#define EPT 4
#define HP2 1088        // hist pitch (u16 entries per digit row)

__global__ __launch_bounds__(SORT_T) void sort_kernel(const float* __restrict__ props,
                                                      const float* __restrict__ scores) {
    const int b = blockIdx.x;
    const int tid = threadIdx.x;
    __shared__ unsigned int K0[NPAD], K1[NPAD];        // 32 KB
    __shared__ unsigned short P0[NPAD], P1[NPAD];      // 16 KB
    __shared__ unsigned short Hs[16 * HP2];            // 34 KB
    __shared__ unsigned int sWT[16];
    __shared__ int s_cnt;
    if (tid == 0) s_cnt = 0;
    __syncthreads();

    int localc = 0;
    {
        const int n0 = tid * EPT;
        unsigned int kk[EPT];
        #pragma unroll
        for (int e = 0; e < EPT; ++e) {
            const int n = n0 + e;
            unsigned int k = 0xFFFFFFu;
            if (n < NBOX) {
                const float2 sc = *reinterpret_cast<const float2*>(scores + ((size_t)b * NBOX + n) * 2);
                const float4 p  = *reinterpret_cast<const float4*>(props  + ((size_t)b * NBOX + n) * 4);
                const float fg = sc.y;
                const float w = __fsub_rn(p.z, p.x);
                const float h = __fsub_rn(p.w, p.y);
                if ((fg > 0.5f) && (w >= 16.0f) && (h >= 16.0f)) {
                    k = 0x3F800000u - __float_as_uint(fg);
                    localc++;
                }
            }
            kk[e] = k;
        }
        *reinterpret_cast<uint4*>(&K0[n0]) = make_uint4(kk[0], kk[1], kk[2], kk[3]);
        ushort4 pp;
        pp.x = (unsigned short)(n0 + 0); pp.y = (unsigned short)(n0 + 1);
        pp.z = (unsigned short)(n0 + 2); pp.w = (unsigned short)(n0 + 3);
        *reinterpret_cast<ushort4*>(&P0[n0]) = pp;
    }
    for (int off = 32; off > 0; off >>= 1) localc += __shfl_down(localc, off);
    if ((tid & 63) == 0) atomicAdd(&s_cnt, localc);

    unsigned int kr[EPT];
    unsigned short pr[EPT];

    for (int pass = 0; pass < 6; ++pass) {
        const int shift = pass * 4;
        const unsigned int*   ksrc = (pass & 1) ? K1 : K0;
        unsigned int*         kdst = (pass & 1) ? K0 : K1;
        const unsigned short* psrc = (pass & 1) ? P1 : P0;
        unsigned short*       pdst = (pass & 1) ? P0 : P1;

        for (int hh = tid; hh < (16 * HP2) / 2; hh += SORT_T)
            reinterpret_cast<unsigned int*>(Hs)[hh] = 0;
        __syncthreads();

        {
            const uint4 kv = *reinterpret_cast<const uint4*>(&ksrc[tid * EPT]);
            kr[0] = kv.x; kr[1] = kv.y; kr[2] = kv.z; kr[3] = kv.w;
            const ushort4 pv = *reinterpret_cast<const ushort4*>(&psrc[tid * EPT]);
            pr[0] = pv.x; pr[1] = pv.y; pr[2] = pv.z; pr[3] = pv.w;
        }
        #pragma unroll
        for (int e = 0; e < EPT; ++e) {
            const unsigned int d = (kr[e] >> shift) & 15u;
            Hs[d * HP2 + tid]++;
        }
        __syncthreads();

        {
            const int d  = tid >> 6;
            const int t0 = (tid & 63) * 16;
            unsigned short* row = &Hs[d * HP2];
            unsigned int sum = 0;
            #pragma unroll
            for (int e = 0; e < 16; ++e) {
                const unsigned int v = row[t0 + e];
                row[t0 + e] = (unsigned short)sum;
                sum += v;
            }
            unsigned int x = sum;
            #pragma unroll
            for (int off = 1; off < 64; off <<= 1) {
                const unsigned int y = __shfl_up(x, off);
                if ((tid & 63) >= off) x += y;
            }
            const int wid = tid >> 6;
            if ((tid & 63) == 63) sWT[wid] = x;
            __syncthreads();
            unsigned int base = x - sum;
            for (int w = 0; w < wid; ++w) base += sWT[w];
            #pragma unroll
            for (int e = 0; e < 16; ++e) row[t0 + e] += (unsigned short)base;
        }
        __syncthreads();

        #pragma unroll
        for (int e = 0; e < EPT; ++e) {
            const unsigned int d = (kr[e] >> shift) & 15u;
            const unsigned int pos = Hs[d * HP2 + tid]++;
            kdst[pos] = kr[e];
            pdst[pos] = pr[e];
        }
        __syncthreads();
    }

    const int nv = s_cnt;
    if (tid == 0) g_nvalid[b] = nv;
    {
        const int p0 = tid * EPT;
        const ushort4 pv = *reinterpret_cast<const ushort4*>(&P0[p0]);
        const unsigned short pe[EPT] = {pv.x, pv.y, pv.z, pv.w};
        #pragma unroll
        for (int e = 0; e < EPT; ++e) {
            const int p = p0 + e;
            if (p < nv) {
                const float4 bx = *reinterpret_cast<const float4*>(props + ((size_t)b * NBOX + pe[e]) * 4);
                g_sorted[b][p] = bx;
                g_area[b][p] = __fmul_rn(__fsub_rn(bx.z, bx.x), __fsub_rn(bx.w, bx.y));
            } else {
                g_sorted[b][p] = make_float4(2e9f, 2e9f, 2e9f, 2e9f);
                g_area[b][p] = 0.0f;
            }
        }
    }
    for (int z = tid; z < 66 * 64; z += SORT_T) (&g_colT[b][0][0])[z] = 0ull;
    for (int z = tid; z < 33 * 64; z += SORT_T) (&g_colTB[b][0][0])[z] = 0ull;
    for (int z = tid; z < 32 * 16; z += SORT_T) (&g_done[b][0][0])[z] = 0u;
}

// ---------------------------------------------------------------------------
// Kernel 2: FUSED iou + nms, single dispatch.
//   blocks 0..7      : nms for batch b = blockIdx.x (spin-waits per SB)
//   blocks 8..32775  : iou row id = blockIdx.x - 8 = b*4096 + i
// Visibility protocol (NO fences in loops — R16's fatal mistake):
//   - g_sup rows   : relaxed AGENT atomic stores (land at MALL; no dirty L2)
//   - colT / colTB : atomicOr (MALL)
//   - completion   : ONE release fetch_add per iou block on g_done[b][i>>7]
//     (release's wbl2 sees a clean L2 -> cheap); nms ACQUIRE-spins until 128.
// Deadlock-free by construction: the <=8 spinning nms blocks occupy <=8 waves,
// iou always has >=248 free CUs to make progress, regardless of placement.
// nms SB s starts as soon as rows [128s,128s+128) are done -> overlaps iou.
// ---------------------------------------------------------------------------
__device__ __forceinline__ unsigned int rdlu(unsigned int v, int l) {
    return (unsigned int)__builtin_amdgcn_readlane((int)v, l);
}
__device__ __forceinline__ u64 rdl64(u64 v, int l) {
    const unsigned lo = rdlu((unsigned)v, l);
    const unsigned hi = rdlu((unsigned)(v >> 32), l);
    return ((u64)hi << 32) | lo;
}

__global__ __launch_bounds__(64) void fused_kernel(float* __restrict__ out) {
    const int lane = threadIdx.x;

    if (blockIdx.x >= BATCH) {
        // ===================== IOU part =====================
        const int id = blockIdx.x - BATCH;     // b*4096 + i
        const int b = id >> 12;
        const int i = id & (NPAD - 1);
        const int nv = g_nvalid[b];
        const int sb = i >> 7;

        if (i < nv) {
            const int c0 = i >> 6;
            const int W = (nv + 63) >> 6;
            const double C = 0.5 - 0x1p-26;    // exact rounding boundary of 0.5

            const float4 bi = g_sorted[b][i];
            const float areai = g_area[b][i];

            u64 myword = 0ull;
            // peeled diagonal chunk c = c0 (the only chunk needing j > i)
            {
                const int j = (c0 << 6) + lane;
                const float4 bj = g_sorted[b][j];
                const float areaj = g_area[b][j];
                const float xi1 = fmaxf(bi.x, bj.x);
                const float yi1 = fmaxf(bi.y, bj.y);
                const float xi2 = fminf(bi.z, bj.z);
                const float yi2 = fminf(bi.w, bj.w);
                const float iw = fmaxf(__fsub_rn(xi2, xi1), 0.0f);
                const float ih = fmaxf(__fsub_rn(yi2, yi1), 0.0f);
                const float inter = __fmul_rn(iw, ih);
                const float uni = __fsub_rn(__fadd_rn(areai, areaj), inter);
                const bool pred = ((double)inter >= (double)uni * C) && (j > i);
                const u64 wd = __ballot(pred);
                if (lane == c0) myword = wd;
                const u64 contrib = ((wd >> lane) & 1ull) << (i & 63);
                if (contrib) atomicOr(&g_colT[b][c0][lane], contrib);
            }
            // off-diagonal chunks: j > i automatic, sentinels handle j >= nv
            for (int c = c0 + 1; c < W; ++c) {
                const int j = (c << 6) + lane;
                const float4 bj = g_sorted[b][j];
                const float areaj = g_area[b][j];
                const float xi1 = fmaxf(bi.x, bj.x);
                const float yi1 = fmaxf(bi.y, bj.y);
                const float xi2 = fminf(bi.z, bj.z);
                const float yi2 = fminf(bi.w, bj.w);
                const float iw = fmaxf(__fsub_rn(xi2, xi1), 0.0f);
                const float ih = fmaxf(__fsub_rn(yi2, yi1), 0.0f);
                const float inter = __fmul_rn(iw, ih);
                const float uni = __fsub_rn(__fadd_rn(areai, areaj), inter);
                const bool pred = ((double)inter >= (double)uni * C);
                const u64 wd = __ballot(pred);
                if (lane == c) myword = wd;
                if (c == c0 + 1 && !(c0 & 1)) {
                    const u64 contrib = ((wd >> lane) & 1ull) << (i & 63);
                    if (contrib) atomicOr(&g_colTB[b][i >> 7][lane], contrib);
                }
            }
            // MALL-visible row store (no dirty L2 line -> later release is cheap)
            __hip_atomic_store(&g_sup[b][i][lane], myword,
                               __ATOMIC_RELAXED, __HIP_MEMORY_SCOPE_AGENT);
        }
        // completion: exactly one release-add per block (also for i >= nv)
        if (lane == 0)
            __hip_atomic_fetch_add(&g_done[b][sb][0], 1u,
                                   __ATOMIC_RELEASE, __HIP_MEMORY_SCOPE_AGENT);
        return;
    }

    // ===================== NMS part (blocks 0..7) =====================
    const int b = blockIdx.x;
    int nv = g_nvalid[b];
    if (nv > NBOX) nv = NBOX;
    float4* outv = reinterpret_cast<float4*>(out) + (size_t)b * MAXK;
    const u64* supb = &g_sup[b][0][0];
    __shared__ int sIdx[128];

    // zero-fill output up-front (off the critical chain)
    for (int s = lane; s < MAXK; s += 64)
        outv[s] = make_float4(0.0f, 0.0f, 0.0f, 0.0f);

    u64 removed = 0ull;                 // lane w holds removed word w
    int kept = 0;
    const int nsb = (nv + 127) >> 7;    // <= 32

    for (int s = 0; s < nsb && kept < MAXK; ++s) {
        const int base = s << 7;

        // wait until this SB's 128 iou rows are complete (acquire pairs with
        // the producers' release-adds; uniform wave-wide spin, s_sleep backoff)
        while (__hip_atomic_load(&g_done[b][s][0], __ATOMIC_ACQUIRE,
                                 __HIP_MEMORY_SCOPE_AGENT) < 128u)
            __builtin_amdgcn_s_sleep(2);

        const u64 cA = g_colT[b][2 * s][lane];
        const u64 cB = g_colT[b][2 * s + 1][lane];
        const u64 cC = g_colTB[b][s][lane];

        const u64 wv0 = rdl64(removed, 2 * s);
        const u64 wv1 = rdl64(removed, 2 * s + 1);
        const int aliveA = (int)((~wv0 >> lane) & 1ull) & (int)(base + lane < nv);
        const int aliveB = (int)((~wv1 >> lane) & 1ull) & (int)(base + 64 + lane < nv);

        // joint Jacobi fixpoint over 128 rows (ballots only; R12/R15-proven)
        u64 balA = __ballot(aliveA != 0);
        u64 balB = __ballot(aliveB != 0);
        while (balA | balB) {
            const int supA = ((cA & balA) != 0ull);
            const int supB = (((cC & balA) | (cB & balB)) != 0ull);
            const u64 nbA = __ballot((aliveA & (supA ^ 1)) != 0);
            const u64 nbB = __ballot((aliveB & (supB ^ 1)) != 0);
            if (nbA == balA && nbB == balB) break;
            balA = nbA; balB = nbB;
        }

        int m = __popcll(balA) + __popcll(balB);
        const int cap = MAXK - kept;
        while (m > cap) {               // trim highest rows (keep greedy prefix)
            if (balB) balB &= ~(1ull << (63 - __builtin_clzll(balB)));
            else      balA &= ~(1ull << (63 - __builtin_clzll(balA)));
            --m;
        }

        if (m > 0) {
            const int mA = __popcll(balA);
            unsigned rA = __builtin_amdgcn_mbcnt_lo((unsigned)balA, 0u);
            rA = __builtin_amdgcn_mbcnt_hi((unsigned)(balA >> 32), rA);
            if ((balA >> lane) & 1ull) sIdx[rA] = base + lane;
            unsigned rB = __builtin_amdgcn_mbcnt_lo((unsigned)balB, 0u);
            rB = __builtin_amdgcn_mbcnt_hi((unsigned)(balB >> 32), rB);
            if ((balB >> lane) & 1ull) sIdx[mA + rB] = base + 64 + lane;

            {
                const int m0 = (m < 64) ? m : 64;
                if (lane < m0) outv[kept + lane] = g_sorted[b][sIdx[lane]];
                if (m > 64 && lane < m - 64) outv[kept + 64 + lane] = g_sorted[b][sIdx[64 + lane]];
            }

            // batched OR of kept rows' full suppression rows (addresses from
            // sIdx; rows are MALL-resident, ONE drain per 32-load group)
            if (kept + m < MAXK && s + 1 < nsb) {
                for (int t = 0; t < m; t += 32) {
#define LDW(j) u64 v##j; {                                                      \
                        int tt = t + j; if (tt >= m) tt = m - 1;                \
                        const int it = sIdx[tt];                                \
                        v##j = supb[(size_t)it * WPR + lane];                   }
                    LDW(0)  LDW(1)  LDW(2)  LDW(3)  LDW(4)  LDW(5)  LDW(6)  LDW(7)
                    LDW(8)  LDW(9)  LDW(10) LDW(11) LDW(12) LDW(13) LDW(14) LDW(15)
                    LDW(16) LDW(17) LDW(18) LDW(19) LDW(20) LDW(21) LDW(22) LDW(23)
                    LDW(24) LDW(25) LDW(26) LDW(27) LDW(28) LDW(29) LDW(30) LDW(31)
#undef LDW
                    const u64 o0 = ((v0 | v1) | (v2 | v3)) | ((v4 | v5) | (v6 | v7));
                    const u64 o1 = ((v8 | v9) | (v10 | v11)) | ((v12 | v13) | (v14 | v15));
                    const u64 o2 = ((v16 | v17) | (v18 | v19)) | ((v20 | v21) | (v22 | v23));
                    const u64 o3 = ((v24 | v25) | (v26 | v27)) | ((v28 | v29) | (v30 | v31));
                    removed |= (o0 | o1) | (o2 | o3);
                }
            }
            kept += m;
        }
    }
}

extern "C" void kernel_launch(void* const* d_in, const int* in_sizes, int n_in,
                              void* d_out, int out_size, void* d_ws, size_t ws_size,
                              hipStream_t stream) {
    const float* props  = (const float*)d_in[0];   // (8,4000,4) f32
    const float* scores = (const float*)d_in[1];   // (8,4000,2) f32
    float* out = (float*)d_out;                    // (8,300,4) f32

    sort_kernel<<<BATCH, SORT_T, 0, stream>>>(props, scores);
    fused_kernel<<<BATCH + NPAD * BATCH, 64, 0, stream>>>(out);
}

// Round 18
// 59.142 us; speedup vs baseline: 11.6050x; 5.6337x over previous
//
#include <hip/hip_runtime.h>

#define NBOX 4000
#define NPAD 4096
#define BATCH 8
#define WPR 64          // 64-bit words per suppression row
#define MAXK 300

typedef unsigned long long u64;

// Static device scratch (deterministic: every consulted value is rewritten
// each call — g_colT is zeroed in sort_kernel before iou ORs into it).
__device__ u64 g_sup[BATCH][NPAD][WPR];            // ~16.8 MB full rows
__device__ u64 g_colT[BATCH][65][64];              // transposed diag blocks
__device__ float4 g_sorted[BATCH][NPAD];           // sorted boxes + sentinels
__device__ float g_area[BATCH][NPAD];              // precomputed areas (0 for pad)
__device__ int g_nvalid[BATCH];

// ---------------------------------------------------------------------------
// Kernel 1: per-batch stable LSD radix sort, 1024 threads x EPT=4 (proven).
// Key k = 0x3F800000 - bits(fg): valid => fg > 0.5 => k in (0, 0x800000),
// fits 24 bits -> 6 passes x 4 bits. Invalid/pad k = 0xFFFFFF sorts last.
// Blocked ownership + digit-major scan preserves jnp.argsort stability.
// Epilogue: sorted boxes, SENTINEL boxes (2e9 -> pred exactly false) for
// p >= nv, per-box areas (same __f*_rn ops), and zeroes g_colT.
// ---------------------------------------------------------------------------
#define SORT_T 1024
#define EPT 4
#define HP2 1088        // hist pitch (u16 entries per digit row)

__global__ __launch_bounds__(SORT_T) void sort_kernel(const float* __restrict__ props,
                                                      const float* __restrict__ scores) {
    const int b = blockIdx.x;
    const int tid = threadIdx.x;
    __shared__ unsigned int K0[NPAD], K1[NPAD];        // 32 KB
    __shared__ unsigned short P0[NPAD], P1[NPAD];      // 16 KB
    __shared__ unsigned short Hs[16 * HP2];            // 34 KB
    __shared__ unsigned int sWT[16];
    __shared__ int s_cnt;
    if (tid == 0) s_cnt = 0;
    __syncthreads();

    // Build keys + payloads (blocked: thread t owns n in [4t, 4t+3]).
    int localc = 0;
    {
        const int n0 = tid * EPT;
        unsigned int kk[EPT];
        #pragma unroll
        for (int e = 0; e < EPT; ++e) {
            const int n = n0 + e;
            unsigned int k = 0xFFFFFFu;
            if (n < NBOX) {
                const float2 sc = *reinterpret_cast<const float2*>(scores + ((size_t)b * NBOX + n) * 2);
                const float4 p  = *reinterpret_cast<const float4*>(props  + ((size_t)b * NBOX + n) * 4);
                const float fg = sc.y;
                const float w = __fsub_rn(p.z, p.x);
                const float h = __fsub_rn(p.w, p.y);
                if ((fg > 0.5f) && (w >= 16.0f) && (h >= 16.0f)) {
                    k = 0x3F800000u - __float_as_uint(fg);
                    localc++;
                }
            }
            kk[e] = k;
        }
        *reinterpret_cast<uint4*>(&K0[n0]) = make_uint4(kk[0], kk[1], kk[2], kk[3]);
        ushort4 pp;
        pp.x = (unsigned short)(n0 + 0); pp.y = (unsigned short)(n0 + 1);
        pp.z = (unsigned short)(n0 + 2); pp.w = (unsigned short)(n0 + 3);
        *reinterpret_cast<ushort4*>(&P0[n0]) = pp;
    }
    for (int off = 32; off > 0; off >>= 1) localc += __shfl_down(localc, off);
    if ((tid & 63) == 0) atomicAdd(&s_cnt, localc);

    unsigned int kr[EPT];
    unsigned short pr[EPT];

    for (int pass = 0; pass < 6; ++pass) {
        const int shift = pass * 4;
        const unsigned int*   ksrc = (pass & 1) ? K1 : K0;
        unsigned int*         kdst = (pass & 1) ? K0 : K1;
        const unsigned short* psrc = (pass & 1) ? P1 : P0;
        unsigned short*       pdst = (pass & 1) ? P0 : P1;

        for (int hh = tid; hh < (16 * HP2) / 2; hh += SORT_T)
            reinterpret_cast<unsigned int*>(Hs)[hh] = 0;
        __syncthreads();

        {
            const uint4 kv = *reinterpret_cast<const uint4*>(&ksrc[tid * EPT]);
            kr[0] = kv.x; kr[1] = kv.y; kr[2] = kv.z; kr[3] = kv.w;
            const ushort4 pv = *reinterpret_cast<const ushort4*>(&psrc[tid * EPT]);
            pr[0] = pv.x; pr[1] = pv.y; pr[2] = pv.z; pr[3] = pv.w;
        }
        #pragma unroll
        for (int e = 0; e < EPT; ++e) {
            const unsigned int d = (kr[e] >> shift) & 15u;
            Hs[d * HP2 + tid]++;
        }
        __syncthreads();

        // digit-major exclusive scan over 16384 counters
        {
            const int d  = tid >> 6;
            const int t0 = (tid & 63) * 16;
            unsigned short* row = &Hs[d * HP2];
            unsigned int sum = 0;
            #pragma unroll
            for (int e = 0; e < 16; ++e) {
                const unsigned int v = row[t0 + e];
                row[t0 + e] = (unsigned short)sum;
                sum += v;
            }
            unsigned int x = sum;
            #pragma unroll
            for (int off = 1; off < 64; off <<= 1) {
                const unsigned int y = __shfl_up(x, off);
                if ((tid & 63) >= off) x += y;
            }
            const int wid = tid >> 6;
            if ((tid & 63) == 63) sWT[wid] = x;
            __syncthreads();
            unsigned int base = x - sum;        // exclusive within wave
            for (int w = 0; w < wid; ++w) base += sWT[w];
            #pragma unroll
            for (int e = 0; e < 16; ++e) row[t0 + e] += (unsigned short)base;
        }
        __syncthreads();

        #pragma unroll
        for (int e = 0; e < EPT; ++e) {
            const unsigned int d = (kr[e] >> shift) & 15u;
            const unsigned int pos = Hs[d * HP2 + tid]++;
            kdst[pos] = kr[e];
            pdst[pos] = pr[e];
        }
        __syncthreads();
    }

    const int nv = s_cnt;
    if (tid == 0) g_nvalid[b] = nv;
    {
        const int p0 = tid * EPT;
        const ushort4 pv = *reinterpret_cast<const ushort4*>(&P0[p0]);
        const unsigned short pe[EPT] = {pv.x, pv.y, pv.z, pv.w};
        #pragma unroll
        for (int e = 0; e < EPT; ++e) {
            const int p = p0 + e;
            if (p < nv) {
                const float4 bx = *reinterpret_cast<const float4*>(props + ((size_t)b * NBOX + pe[e]) * 4);
                g_sorted[b][p] = bx;
                g_area[b][p] = __fmul_rn(__fsub_rn(bx.z, bx.x), __fsub_rn(bx.w, bx.y));
            } else {
                g_sorted[b][p] = make_float4(2e9f, 2e9f, 2e9f, 2e9f);
                g_area[b][p] = 0.0f;
            }
        }
    }
    // zero this batch's colT (consumed by iou's atomicOr, then nms)
    for (int z = tid; z < 65 * 64; z += SORT_T)
        (&g_colT[b][0][0])[z] = 0ull;
}

// ---------------------------------------------------------------------------
// Kernel 2: suppression bitmask rows (triangular) + FUSED colT scatter.
// XCD-AFFINITY 1D grid id = i*8 + b (R12-proven): batch b's blocks land on
// XCD b, so g_sup/g_colT stay in the L2 that nms block b reads. All 256 CUs
// stay busy (each XCD runs its own batch's 4000 blocks). The peeled c==c0
// iteration keeps the j>i guard; for c>c0, j>i holds identically, and the
// j<nv guard is gone (sentinel boxes yield pred=false exactly: iw=0,
// areaj=0 => inter/uni = 0/areai = 0 < 0.5). At c==c0 every lane already
// holds the full diagonal word wd (ballot), so lane j ORs its bit into the
// transposed column g_colT[b][c0][j] directly — no separate colT kernel.
// OR is commutative => order-independent => deterministic.
// ---------------------------------------------------------------------------
__global__ __launch_bounds__(64) void iou_kernel() {
    const int id = blockIdx.x;
    const int b = id & (BATCH - 1);
    const int i = id >> 3;
    const int nv = g_nvalid[b];
    if (i >= nv) return;
    const int lane = threadIdx.x;
    const int c0 = i >> 6;
    const int W = (nv + 63) >> 6;

    const float4 bi = g_sorted[b][i];
    const float areai = g_area[b][i];

    u64 myword = 0ull;
    // peeled diagonal chunk c = c0 (the only chunk needing j > i)
    {
        const int j = (c0 << 6) + lane;
        const float4 bj = g_sorted[b][j];
        const float areaj = g_area[b][j];
        const float xi1 = fmaxf(bi.x, bj.x);
        const float yi1 = fmaxf(bi.y, bj.y);
        const float xi2 = fminf(bi.z, bj.z);
        const float yi2 = fminf(bi.w, bj.w);
        const float iw = fmaxf(__fsub_rn(xi2, xi1), 0.0f);
        const float ih = fmaxf(__fsub_rn(yi2, yi1), 0.0f);
        const float inter = __fmul_rn(iw, ih);
        const float uni = __fsub_rn(__fadd_rn(areai, areaj), inter);
        const bool pred = ((inter / uni) >= 0.5f) && (j > i);
        const u64 wd = __ballot(pred);
        if (lane == c0) myword = wd;
        // fused transposed-column scatter: lane j owns column j of tile c0
        const u64 contrib = ((wd >> lane) & 1ull) << (i & 63);
        if (contrib) atomicOr(&g_colT[b][c0][lane], contrib);
    }
    // off-diagonal chunks: j > i automatic, sentinels handle j >= nv
    for (int c = c0 + 1; c < W; ++c) {
        const int j = (c << 6) + lane;
        const float4 bj = g_sorted[b][j];
        const float areaj = g_area[b][j];
        const float xi1 = fmaxf(bi.x, bj.x);
        const float yi1 = fmaxf(bi.y, bj.y);
        const float xi2 = fminf(bi.z, bj.z);
        const float yi2 = fminf(bi.w, bj.w);
        const float iw = fmaxf(__fsub_rn(xi2, xi1), 0.0f);
        const float ih = fmaxf(__fsub_rn(yi2, yi1), 0.0f);
        const float inter = __fmul_rn(iw, ih);
        const float uni = __fsub_rn(__fadd_rn(areai, areaj), inter);
        const bool pred = (inter / uni) >= 0.5f;
        const u64 wd = __ballot(pred);
        if (lane == c) myword = wd;
    }
    g_sup[b][i][lane] = myword;
}

// ---------------------------------------------------------------------------
// Kernel 3: greedy scan, one wave per batch, JACOBI-FIXPOINT greedy (R12-
// proven): keep <- alive & ((ballot(keep) & colT) == 0) converges to the
// serial-greedy fixpoint in chain-depth+1 ballots (strict lower-triangular
// recurrence => unique fixpoint). Kept-index extraction via sIdx (mbcnt
// rank + LDS scatter); OR-load addresses are parallel sIdx broadcast reads.
// Cross-block OR: batched named-reg loads, L2-local under XCD affinity,
// ONE drain per 32-load group.
// ---------------------------------------------------------------------------
__device__ __forceinline__ unsigned int rdlu(unsigned int v, int l) {
    return (unsigned int)__builtin_amdgcn_readlane((int)v, l);
}
__device__ __forceinline__ u64 rdl64(u64 v, int l) {
    const unsigned lo = rdlu((unsigned)v, l);
    const unsigned hi = rdlu((unsigned)(v >> 32), l);
    return ((u64)hi << 32) | lo;
}

__global__ __launch_bounds__(64) void nms_kernel(float* __restrict__ out) {
    const int b = blockIdx.x;
    const int lane = threadIdx.x;
    int nv = g_nvalid[b];
    if (nv > NBOX) nv = NBOX;
    float4* outv = reinterpret_cast<float4*>(out) + (size_t)b * MAXK;
    const u64* supb = &g_sup[b][0][0];
    __shared__ int sIdx[64];

    // zero-fill output up-front (off the critical chain)
    for (int s = lane; s < MAXK; s += 64)
        outv[s] = make_float4(0.0f, 0.0f, 0.0f, 0.0f);

    u64 removed = 0ull;                 // lane w holds removed word w
    int kept = 0;
    const int nblk = (nv + 63) >> 6;    // <= 63

    u64 colT = g_colT[b][0][lane];      // column lane of diagonal block 0

    for (int blk = 0; blk < nblk && kept < MAXK; ++blk) {
        const int base = blk << 6;
        // prefetch next block's transposed column (padded array, in-bounds)
        const u64 colT_n = g_colT[b][blk + 1][lane];

        // incoming suppression word for this block (2 readlanes, once/block)
        const u64 wv = rdl64(removed, blk);
        const int alive = (int)((~wv >> lane) & 1ull) & (int)(base + lane < nv);

        // Jacobi fixpoint (ballots only; no per-kept-row serial loop)
        u64 bal = __ballot(alive != 0);
        while (bal != 0ull) {
            const int sup = ((colT & bal) != 0ull);
            const u64 nb = __ballot((alive & (sup ^ 1)) != 0);
            if (nb == bal) break;
            bal = nb;
        }

        int m = __popcll(bal);
        const int cap = MAXK - kept;
        while (m > cap) {               // rare: only the final block
            bal &= ~(1ull << (63 - __builtin_clzll(bal)));
            --m;
        }

        if (m > 0) {
            // rank-compact kept indices via mbcnt + LDS (same-wave, no barrier)
            unsigned rank = __builtin_amdgcn_mbcnt_lo((unsigned)bal, 0u);
            rank = __builtin_amdgcn_mbcnt_hi((unsigned)(bal >> 32), rank);
            if ((bal >> lane) & 1ull) sIdx[rank] = base + lane;
            const int myIdx = sIdx[lane];      // valid for lane < m
            if (lane < m) outv[kept + lane] = g_sorted[b][myIdx];

            // batched OR of kept rows' full suppression rows; addresses come
            // from parallel sIdx broadcast reads (not a serial ctz chain)
            if (kept + m < MAXK && blk + 1 < nblk) {
                for (int t = 0; t < m; t += 32) {
#define LDW(j) u64 v##j; {                                                      \
                        int tt = t + j; if (tt >= m) tt = m - 1;                \
                        const int it = sIdx[tt];                                \
                        v##j = supb[(size_t)it * WPR + lane];                   }
                    LDW(0)  LDW(1)  LDW(2)  LDW(3)  LDW(4)  LDW(5)  LDW(6)  LDW(7)
                    LDW(8)  LDW(9)  LDW(10) LDW(11) LDW(12) LDW(13) LDW(14) LDW(15)
                    LDW(16) LDW(17) LDW(18) LDW(19) LDW(20) LDW(21) LDW(22) LDW(23)
                    LDW(24) LDW(25) LDW(26) LDW(27) LDW(28) LDW(29) LDW(30) LDW(31)
#undef LDW
                    const u64 o0 = ((v0 | v1) | (v2 | v3)) | ((v4 | v5) | (v6 | v7));
                    const u64 o1 = ((v8 | v9) | (v10 | v11)) | ((v12 | v13) | (v14 | v15));
                    const u64 o2 = ((v16 | v17) | (v18 | v19)) | ((v20 | v21) | (v22 | v23));
                    const u64 o3 = ((v24 | v25) | (v26 | v27)) | ((v28 | v29) | (v30 | v31));
                    removed |= (o0 | o1) | (o2 | o3);
                }
            }
            kept += m;
        }
        colT = colT_n;
    }
}

extern "C" void kernel_launch(void* const* d_in, const int* in_sizes, int n_in,
                              void* d_out, int out_size, void* d_ws, size_t ws_size,
                              hipStream_t stream) {
    const float* props  = (const float*)d_in[0];   // (8,4000,4) f32
    const float* scores = (const float*)d_in[1];   // (8,4000,2) f32
    float* out = (float*)d_out;                    // (8,300,4) f32

    sort_kernel<<<BATCH, SORT_T, 0, stream>>>(props, scores);
    iou_kernel<<<NBOX * BATCH, 64, 0, stream>>>();        // id = i*8 + b
    nms_kernel<<<BATCH, 64, 0, stream>>>(out);
}